// Round 4
// baseline (289.998 us; speedup 1.0000x reference)
//
#include <hip/hip_runtime.h>
#include <math.h>

// Problem constants (B=16, N=128, D=64, T=96)
#define BN   2048
#define BN2  4096
#define DD   64
#define TT   96
#define NCH  128
#define TPB  256
#define RPB  8

// k_sig tiling: 8 p-rows x 512 cols per block, 2 cols/thread
#define SCHUNK 512
#define SNCH   (BN / SCHUNK)             // 4
#define SGRID  ((BN / RPB) * SNCH)       // 1024

// k_rows tiling: 8 rows x 1024 cols per block, 2 cols/thread (2 iters)
#define RCHUNK 1024
#define RNCH   (BN / RCHUNK)             // 2
#define RGRID  ((BN2 / RPB) * RNCH)      // 1024

// ws layout (floats), total ~4.42M floats ~17.7 MB
#define ST_OFF  0                         // [BN][TT] transposed series
#define SSQ_OFF (ST_OFF + BN * TT)        // [BN]
#define SLV_OFF (SSQ_OFF + BN)            // [BN][BN] sigmoid matrix
#define RS_OFF  (SLV_OFF + BN * BN)       // [BN][SNCH] rowsum partials
#define SLT_OFF (RS_OFF + BN * SNCH)      // [SGRID] grand-total partials
#define SR_OFF  (SLT_OFF + SGRID)         // [BN2][RNCH] softmax-denom partials
#define BR_OFF  (SR_OFF + BN2 * RNCH)     // [BN2][RNCH] B partials

#define FMA4(acc, v, q) acc = fmaf((v).x,(q).x, fmaf((v).y,(q).y, fmaf((v).z,(q).z, fmaf((v).w,(q).w,(acc)))))

__device__ __forceinline__ void smax_merge(float& m, float& s, float mo, float so) {
  float nm = fmaxf(m, mo);
  s = s * __expf(m - nm) + so * __expf(mo - nm);
  m = nm;
}

__device__ __forceinline__ float dot64(const float* a, const float* b) {
  float acc = 0.f;
#pragma unroll
  for (int d4 = 0; d4 < DD / 4; ++d4) {
    float4 x = ((const float4*)a)[d4], y = ((const float4*)b)[d4];
    acc = fmaf(x.x, y.x, fmaf(x.y, y.y, fmaf(x.z, y.z, fmaf(x.w, y.w, acc))));
  }
  return acc;
}

// ---------------- k_pre: transpose series + per-row ssq ----------------
__global__ __launch_bounds__(TPB) void k_pre(const float* __restrict__ os,
                                             float* __restrict__ ws)
{
  float* ST  = ws + ST_OFF;
  float* SSQ = ws + SSQ_OFF;
  const int b = blockIdx.x, tid = threadIdx.x;
  if (b < 768) {                 // 768*256 = BN*TT
    int g = b * TPB + tid;
    int p = g / TT, t = g - p * TT;
    ST[g] = os[((p >> 7) * TT + t) * NCH + (p & (NCH - 1))];
  } else {                       // 8*256 = BN
    int p = (b - 768) * TPB + tid;
    const float* sp = os + (p >> 7) * TT * NCH + (p & (NCH - 1));
    float acc = 0.f;
    for (int t = 0; t < TT; ++t) { float v = sp[t * NCH]; acc = fmaf(v, v, acc); }
    SSQ[p] = acc;
  }
}

// ---------------- k_sig: sigmoid matrix + rowsums + total ----------------
__global__ __launch_bounds__(TPB) void k_sig(float* __restrict__ ws)
{
  const float* ST  = ws + ST_OFF;
  const float* SSQ = ws + SSQ_OFF;
  float* SLV = ws + SLV_OFF;
  float* RS  = ws + RS_OFF;
  float* SLT = ws + SLT_OFF;
  __shared__ float redrs[4][RPB], redt[4];

  const int tid = threadIdx.x;
  const int rg = blockIdx.x >> 2, chunk = blockIdx.x & 3;
  const int p0 = rg * RPB;
  const int ca = chunk * SCHUNK + tid, cb = ca + TPB;

  const float* srow[RPB]; float ssqR[RPB];
#pragma unroll
  for (int r = 0; r < RPB; ++r) { srow[r] = ST + (size_t)(p0 + r) * TT; ssqR[r] = SSQ[p0 + r]; }

  float sda[RPB], sdb[RPB];
#pragma unroll
  for (int r = 0; r < RPB; ++r) { sda[r] = 0.f; sdb[r] = 0.f; }
  const float4* pa = (const float4*)(ST + (size_t)ca * TT);
  const float4* pb = (const float4*)(ST + (size_t)cb * TT);
#pragma unroll 4
  for (int t4 = 0; t4 < TT / 4; ++t4) {
    float4 va = pa[t4], vb = pb[t4];
#pragma unroll
    for (int r = 0; r < RPB; ++r) {
      float4 q = *(const float4*)(srow[r] + t4 * 4);   // uniform -> s_load
      FMA4(sda[r], va, q);
      FMA4(sdb[r], vb, q);
    }
  }
  const float ssqa = SSQ[ca], ssqb = SSQ[cb];
  float tot = 0.f, rsr[RPB];
#pragma unroll
  for (int r = 0; r < RPB; ++r) {
    float da = ssqR[r] + ssqa - 2.f * sda[r];
    float db = ssqR[r] + ssqb - 2.f * sdb[r];
    float la = __builtin_amdgcn_rcpf(1.f + __expf(0.5f * da));
    float lb = __builtin_amdgcn_rcpf(1.f + __expf(0.5f * db));
    SLV[(size_t)(p0 + r) * BN + ca] = la;
    SLV[(size_t)(p0 + r) * BN + cb] = lb;
    rsr[r] = la + lb; tot += la + lb;
  }
#pragma unroll
  for (int off = 32; off; off >>= 1) {
#pragma unroll
    for (int r = 0; r < RPB; ++r) rsr[r] += __shfl_xor(rsr[r], off);
    tot += __shfl_xor(tot, off);
  }
  const int w = tid >> 6;
  if ((tid & 63) == 0) {
#pragma unroll
    for (int r = 0; r < RPB; ++r) redrs[w][r] = rsr[r];
    redt[w] = tot;
  }
  __syncthreads();
  if (tid < RPB)
    RS[(size_t)(p0 + tid) * SNCH + chunk] = redrs[0][tid] + redrs[1][tid] + redrs[2][tid] + redrs[3][tid];
  if (tid == 0) SLT[blockIdx.x] = redt[0] + redt[1] + redt[2] + redt[3];
}

// ---------------- k_rows: softmax-denoms + B sums ----------------
__global__ __launch_bounds__(TPB, 4) void k_rows(
    const float* __restrict__ of, const float* __restrict__ af,
    float* __restrict__ ws)
{
  const float* SLV = ws + SLV_OFF;
  float* SR = ws + SR_OFF;
  float* BR = ws + BR_OFF;
  __shared__ float redS[4][RPB], redB[4][RPB];

  const int tid = threadIdx.x;
  const int rg = blockIdx.x >> 1, chunk = blockIdx.x & 1;
  const int i0 = rg * RPB;
  const int p0 = i0 & (BN - 1);
  const bool half1 = (i0 >= BN);          // block-uniform (rows don't straddle)
  const int c0 = chunk * RCHUNK;

  const float* frow[RPB];
#pragma unroll
  for (int r = 0; r < RPB; ++r) {
    const int i = i0 + r;
    frow[r] = (i < BN) ? of + (size_t)i * DD : af + (size_t)(i - BN) * DD;
  }

  float s[RPB], Bb[RPB];
#pragma unroll
  for (int r = 0; r < RPB; ++r) { s[r] = 0.f; Bb[r] = 0.f; }

  for (int d = 0; d < RCHUNK / (2 * TPB); ++d) {
    const int ca = c0 + d * (2 * TPB) + tid;
    const int cb = ca + TPB;

    float a00[RPB], a10[RPB], a01[RPB], a11[RPB];
#pragma unroll
    for (int r = 0; r < RPB; ++r) { a00[r] = 0.f; a10[r] = 0.f; a01[r] = 0.f; a11[r] = 0.f; }
    const float4* pA0 = (const float4*)(of + (size_t)ca * DD);
    const float4* pB0 = (const float4*)(af + (size_t)ca * DD);
    const float4* pA1 = (const float4*)(of + (size_t)cb * DD);
    const float4* pB1 = (const float4*)(af + (size_t)cb * DD);
#pragma unroll 4
    for (int d4 = 0; d4 < DD / 4; ++d4) {
      float4 A0 = pA0[d4], B0 = pB0[d4], A1 = pA1[d4], B1 = pB1[d4];
#pragma unroll
      for (int r = 0; r < RPB; ++r) {
        float4 f = *(const float4*)(frow[r] + d4 * 4);   // uniform -> s_load
        FMA4(a00[r], A0, f);
        FMA4(a10[r], B0, f);
        FMA4(a01[r], A1, f);
        FMA4(a11[r], B1, f);
      }
    }
#pragma unroll
    for (int r = 0; r < RPB; ++r) {
      const int pr = p0 + r;
      const float la = SLV[(size_t)pr * BN + ca];
      const float lb = SLV[(size_t)pr * BN + cb];
      // mask ONLY the diagonal in-loop (exp(sim_ii) may overflow fp32)
      const bool da = (ca == pr), db = (cb == pr);
      float v00 = a00[r], v10 = a10[r], v01 = a01[r], v11 = a11[r];
      if (!half1) { v00 = da ? -1e30f : v00; v01 = db ? -1e30f : v01; }
      else        { v10 = da ? -1e30f : v10; v11 = db ? -1e30f : v11; }
      s[r] += __expf(v00) + __expf(v10) + __expf(v01) + __expf(v11);
      Bb[r] = fmaf(la, a00[r] + a10[r], fmaf(lb, a01[r] + a11[r], Bb[r]));
    }
  }

#pragma unroll
  for (int off = 32; off; off >>= 1) {
#pragma unroll
    for (int r = 0; r < RPB; ++r) {
      s[r]  += __shfl_xor(s[r],  off);
      Bb[r] += __shfl_xor(Bb[r], off);
    }
  }
  const int w = tid >> 6;
  if ((tid & 63) == 0) {
#pragma unroll
    for (int r = 0; r < RPB; ++r) { redS[w][r] = s[r]; redB[w][r] = Bb[r]; }
  }
  __syncthreads();
  if (tid < RPB) {
    SR[(size_t)(i0 + tid) * RNCH + chunk] = redS[0][tid] + redS[1][tid] + redS[2][tid] + redS[3][tid];
    BR[(size_t)(i0 + tid) * RNCH + chunk] = redB[0][tid] + redB[1][tid] + redB[2][tid] + redB[3][tid];
  }
}

// ---------------- k_final: per-row corrections + global reduce ----------------
__global__ __launch_bounds__(1024) void k_final(
    const float* __restrict__ of, const float* __restrict__ af,
    const float* __restrict__ ws, float* __restrict__ out)
{
  const float* SLV = ws + SLV_OFF;
  const float* RS  = ws + RS_OFF;
  const float* SLT = ws + SLT_OFF;
  const float* SR  = ws + SR_OFF;
  const float* BR  = ws + BR_OFF;
  __shared__ float redL[1024], redT[1024];
  const int tid = threadIdx.x;

  float loss = 0.f;
#pragma unroll
  for (int t = 0; t < BN2 / 1024; ++t) {
    const int i = t * 1024 + tid;
    const int p = i & (BN - 1);
    float S  = SR[(size_t)i * RNCH] + SR[(size_t)i * RNCH + 1];
    float Bv = BR[(size_t)i * RNCH] + BR[(size_t)i * RNCH + 1];
    float rsum = 0.f;
#pragma unroll
    for (int k = 0; k < SNCH; ++k) rsum += RS[(size_t)p * SNCH + k];
    const float* fi = (i < BN) ? of + (size_t)i * DD : af + (size_t)(i - BN) * DD;
    const float sii  = dot64(fi, fi);
    const float slpp = SLV[(size_t)p * BN + p];
    float Av = 2.f * rsum - slpp;       // remove diag from A
    Bv -= sii * slpp;                   // remove diag from B (loop included it)
    float M = 0.f;
    if (i >= 1) {
      const int j = i - 1;
      const float* f1 = (j < BN) ? of + (size_t)j * DD : af + (size_t)(j - BN) * DD;
      const float sim1 = dot64(fi, f1);
      const float sl1  = SLV[(size_t)p * BN + (j & (BN - 1))];
      S -= __expf(sim1); Av -= sl1; Bv -= sim1 * sl1;
      const float e2 = sim1 + sii, snd2 = sl1 + 0.5f;   // sl[i][i] = 0.5 exactly in ref
      if (i >= 2) {
        const int j2 = i - 2;
        const float* f2 = (j2 < BN) ? of + (size_t)j2 * DD : af + (size_t)(j2 - BN) * DD;
        const float sim2 = dot64(fi, f2);
        const float sl2  = SLV[(size_t)p * BN + (j2 & (BN - 1))];
        S -= __expf(sim2); Av -= sl2; Bv -= sim2 * sl2;
        const float e1 = sim2 + sim1, snd1 = sl2 + sl1;
        smax_merge(M, S, e1, 1.f); Av += snd1; Bv = fmaf(e1, snd1, Bv);
      }
      smax_merge(M, S, e2, 1.f); Av += snd2; Bv = fmaf(e2, snd2, Bv);
    }
    loss += (M + logf(S)) * Av - Bv;
  }
  float tot = SLT[tid];   // SGRID == 1024

  redL[tid] = loss; redT[tid] = tot;
  __syncthreads();
  for (int off = 512; off; off >>= 1) {
    if (tid < off) { redL[tid] += redL[tid + off]; redT[tid] += redT[tid + off]; }
    __syncthreads();
  }
  if (tid == 0) {
    out[0] = redL[0] / (float)((long long)BN2 * (BN2 - 1));
    out[1] = redT[0] / (float)((long long)BN * BN);
  }
}

extern "C" void kernel_launch(void* const* d_in, const int* in_sizes, int n_in,
                              void* d_out, int out_size, void* d_ws, size_t ws_size,
                              hipStream_t stream) {
  (void)in_sizes; (void)n_in; (void)out_size; (void)ws_size;
  const float* of = (const float*)d_in[0];   // original_feature  (16,128,64)
  const float* af = (const float*)d_in[1];   // augmented_feature (16,128,64)
  const float* os = (const float*)d_in[2];   // original_series   (16,96,128)
  float* ws = (float*)d_ws;
  k_pre  <<<776,  TPB,  0, stream>>>(os, ws);
  k_sig  <<<SGRID, TPB, 0, stream>>>(ws);
  k_rows <<<RGRID, TPB, 0, stream>>>(of, af, ws);
  k_final<<<1,    1024, 0, stream>>>(of, af, ws, (float*)d_out);
}

// Round 5
// 130.729 us; speedup vs baseline: 2.2183x; 2.2183x over previous
//
#include <hip/hip_runtime.h>
#include <math.h>

// Problem constants (B=16, N=128, D=64, T=96)
#define BN   2048
#define BN2  4096
#define DD   64
#define TT   96
#define NCH  128
#define TPB  256
#define RPB  8

// k_sig tiling: 8 p-rows x 512 cols per block, 2 cols/thread
#define SCHUNK 512
#define SNCH   (BN / SCHUNK)             // 4
#define SGRID  ((BN / RPB) * SNCH)       // 1024

// k_rows tiling: 8 rows x 1024 cols per block, 2 cols/thread (2 iters)
#define RCHUNK 1024
#define RNCH   (BN / RCHUNK)             // 2
#define RGRID  ((BN2 / RPB) * RNCH)      // 1024

// ws layout (floats)
#define ST_OFF   0                         // [BN][TT] transposed series
#define SSQ_OFF  (ST_OFF + BN * TT)        // [BN]
#define SLV_OFF  (SSQ_OFF + BN)            // [BN][BN] sigmoid matrix
#define RS_OFF   (SLV_OFF + BN * BN)       // [BN][SNCH] rowsum partials
#define SLT_OFF  (RS_OFF + BN * SNCH)      // [SGRID] grand-total partials
#define SR_OFF   (SLT_OFF + SGRID)         // [BN2][RNCH] softmax-denom partials
#define BR_OFF   (SR_OFF + BN2 * RNCH)     // [BN2][RNCH] B partials
#define ROWL_OFF (BR_OFF + BN2 * RNCH)     // [BN2] per-row loss

#define FMA4(acc, v, q) acc = fmaf((v).x,(q).x, fmaf((v).y,(q).y, fmaf((v).z,(q).z, fmaf((v).w,(q).w,(acc)))))

__device__ __forceinline__ void smax_merge(float& m, float& s, float mo, float so) {
  float nm = fmaxf(m, mo);
  s = s * __expf(m - nm) + so * __expf(mo - nm);
  m = nm;
}

__device__ __forceinline__ float dot64(const float* a, const float* b) {
  float acc = 0.f;
#pragma unroll
  for (int d4 = 0; d4 < DD / 4; ++d4) {
    float4 x = ((const float4*)a)[d4], y = ((const float4*)b)[d4];
    acc = fmaf(x.x, y.x, fmaf(x.y, y.y, fmaf(x.z, y.z, fmaf(x.w, y.w, acc))));
  }
  return acc;
}

// ---------------- k_pre: transpose series + per-row ssq ----------------
__global__ __launch_bounds__(TPB) void k_pre(const float* __restrict__ os,
                                             float* __restrict__ ws)
{
  float* ST  = ws + ST_OFF;
  float* SSQ = ws + SSQ_OFF;
  const int b = blockIdx.x, tid = threadIdx.x;
  if (b < 768) {                 // 768*256 = BN*TT
    int g = b * TPB + tid;
    int p = g / TT, t = g - p * TT;
    ST[g] = os[((p >> 7) * TT + t) * NCH + (p & (NCH - 1))];
  } else {                       // 8*256 = BN
    int p = (b - 768) * TPB + tid;
    const float* sp = os + (p >> 7) * TT * NCH + (p & (NCH - 1));
    float acc = 0.f;
    for (int t = 0; t < TT; ++t) { float v = sp[t * NCH]; acc = fmaf(v, v, acc); }
    SSQ[p] = acc;
  }
}

// ---------------- k_sig: sigmoid matrix + rowsums + total ----------------
__global__ __launch_bounds__(TPB) void k_sig(float* __restrict__ ws)
{
  const float* ST  = ws + ST_OFF;
  const float* SSQ = ws + SSQ_OFF;
  float* SLV = ws + SLV_OFF;
  float* RS  = ws + RS_OFF;
  float* SLT = ws + SLT_OFF;
  __shared__ float redrs[4][RPB], redt[4];

  const int tid = threadIdx.x;
  const int rg = blockIdx.x >> 2, chunk = blockIdx.x & 3;
  const int p0 = rg * RPB;
  const int ca = chunk * SCHUNK + tid, cb = ca + TPB;

  const float* srow[RPB]; float ssqR[RPB];
#pragma unroll
  for (int r = 0; r < RPB; ++r) { srow[r] = ST + (size_t)(p0 + r) * TT; ssqR[r] = SSQ[p0 + r]; }

  float sda[RPB], sdb[RPB];
#pragma unroll
  for (int r = 0; r < RPB; ++r) { sda[r] = 0.f; sdb[r] = 0.f; }
  const float4* pa = (const float4*)(ST + (size_t)ca * TT);
  const float4* pb = (const float4*)(ST + (size_t)cb * TT);
#pragma unroll 4
  for (int t4 = 0; t4 < TT / 4; ++t4) {
    float4 va = pa[t4], vb = pb[t4];
#pragma unroll
    for (int r = 0; r < RPB; ++r) {
      float4 q = *(const float4*)(srow[r] + t4 * 4);   // uniform -> s_load
      FMA4(sda[r], va, q);
      FMA4(sdb[r], vb, q);
    }
  }
  const float ssqa = SSQ[ca], ssqb = SSQ[cb];
  float tot = 0.f, rsr[RPB];
#pragma unroll
  for (int r = 0; r < RPB; ++r) {
    float da = ssqR[r] + ssqa - 2.f * sda[r];
    float db = ssqR[r] + ssqb - 2.f * sdb[r];
    float la = __builtin_amdgcn_rcpf(1.f + __expf(0.5f * da));
    float lb = __builtin_amdgcn_rcpf(1.f + __expf(0.5f * db));
    SLV[(size_t)(p0 + r) * BN + ca] = la;
    SLV[(size_t)(p0 + r) * BN + cb] = lb;
    rsr[r] = la + lb; tot += la + lb;
  }
#pragma unroll
  for (int off = 32; off; off >>= 1) {
#pragma unroll
    for (int r = 0; r < RPB; ++r) rsr[r] += __shfl_xor(rsr[r], off);
    tot += __shfl_xor(tot, off);
  }
  const int w = tid >> 6;
  if ((tid & 63) == 0) {
#pragma unroll
    for (int r = 0; r < RPB; ++r) redrs[w][r] = rsr[r];
    redt[w] = tot;
  }
  __syncthreads();
  if (tid < RPB)
    RS[(size_t)(p0 + tid) * SNCH + chunk] = redrs[0][tid] + redrs[1][tid] + redrs[2][tid] + redrs[3][tid];
  if (tid == 0) SLT[blockIdx.x] = redt[0] + redt[1] + redt[2] + redt[3];
}

// ---------------- k_rows: softmax-denoms + B sums ----------------
__global__ __launch_bounds__(TPB, 4) void k_rows(
    const float* __restrict__ of, const float* __restrict__ af,
    float* __restrict__ ws)
{
  const float* SLV = ws + SLV_OFF;
  float* SR = ws + SR_OFF;
  float* BR = ws + BR_OFF;
  __shared__ float redS[4][RPB], redB[4][RPB];

  const int tid = threadIdx.x;
  const int rg = blockIdx.x >> 1, chunk = blockIdx.x & 1;
  const int i0 = rg * RPB;
  const int p0 = i0 & (BN - 1);
  const bool half1 = (i0 >= BN);          // block-uniform (rows don't straddle)
  const int c0 = chunk * RCHUNK;

  const float* frow[RPB];
#pragma unroll
  for (int r = 0; r < RPB; ++r) {
    const int i = i0 + r;
    frow[r] = (i < BN) ? of + (size_t)i * DD : af + (size_t)(i - BN) * DD;
  }

  float s[RPB], Bb[RPB];
#pragma unroll
  for (int r = 0; r < RPB; ++r) { s[r] = 0.f; Bb[r] = 0.f; }

  for (int d = 0; d < RCHUNK / (2 * TPB); ++d) {
    const int ca = c0 + d * (2 * TPB) + tid;
    const int cb = ca + TPB;

    float a00[RPB], a10[RPB], a01[RPB], a11[RPB];
#pragma unroll
    for (int r = 0; r < RPB; ++r) { a00[r] = 0.f; a10[r] = 0.f; a01[r] = 0.f; a11[r] = 0.f; }
    const float4* pA0 = (const float4*)(of + (size_t)ca * DD);
    const float4* pB0 = (const float4*)(af + (size_t)ca * DD);
    const float4* pA1 = (const float4*)(of + (size_t)cb * DD);
    const float4* pB1 = (const float4*)(af + (size_t)cb * DD);
#pragma unroll 4
    for (int d4 = 0; d4 < DD / 4; ++d4) {
      float4 A0 = pA0[d4], B0 = pB0[d4], A1 = pA1[d4], B1 = pB1[d4];
#pragma unroll
      for (int r = 0; r < RPB; ++r) {
        float4 f = *(const float4*)(frow[r] + d4 * 4);   // uniform -> s_load
        FMA4(a00[r], A0, f);
        FMA4(a10[r], B0, f);
        FMA4(a01[r], A1, f);
        FMA4(a11[r], B1, f);
      }
    }
#pragma unroll
    for (int r = 0; r < RPB; ++r) {
      const int pr = p0 + r;
      const float la = SLV[(size_t)pr * BN + ca];
      const float lb = SLV[(size_t)pr * BN + cb];
      // mask ONLY the diagonal in-loop (exp(sim_ii) may overflow fp32)
      const bool da = (ca == pr), db = (cb == pr);
      float v00 = a00[r], v10 = a10[r], v01 = a01[r], v11 = a11[r];
      if (!half1) { v00 = da ? -1e30f : v00; v01 = db ? -1e30f : v01; }
      else        { v10 = da ? -1e30f : v10; v11 = db ? -1e30f : v11; }
      s[r] += __expf(v00) + __expf(v10) + __expf(v01) + __expf(v11);
      Bb[r] = fmaf(la, a00[r] + a10[r], fmaf(lb, a01[r] + a11[r], Bb[r]));
    }
  }

#pragma unroll
  for (int off = 32; off; off >>= 1) {
#pragma unroll
    for (int r = 0; r < RPB; ++r) {
      s[r]  += __shfl_xor(s[r],  off);
      Bb[r] += __shfl_xor(Bb[r], off);
    }
  }
  const int w = tid >> 6;
  if ((tid & 63) == 0) {
#pragma unroll
    for (int r = 0; r < RPB; ++r) { redS[w][r] = s[r]; redB[w][r] = Bb[r]; }
  }
  __syncthreads();
  if (tid < RPB) {
    SR[(size_t)(i0 + tid) * RNCH + chunk] = redS[0][tid] + redS[1][tid] + redS[2][tid] + redS[3][tid];
    BR[(size_t)(i0 + tid) * RNCH + chunk] = redB[0][tid] + redB[1][tid] + redB[2][tid] + redB[3][tid];
  }
}

// ---------------- k_corr: per-row corrections (parallel) ----------------
__global__ __launch_bounds__(TPB) void k_corr(
    const float* __restrict__ of, const float* __restrict__ af,
    float* __restrict__ ws)
{
  const float* SLV = ws + SLV_OFF;
  const float* RS  = ws + RS_OFF;
  const float* SR  = ws + SR_OFF;
  const float* BR  = ws + BR_OFF;
  float* ROWL = ws + ROWL_OFF;

  const int i = blockIdx.x * TPB + threadIdx.x;   // one row per thread
  const int p = i & (BN - 1);
  float S  = SR[(size_t)i * RNCH] + SR[(size_t)i * RNCH + 1];
  float Bv = BR[(size_t)i * RNCH] + BR[(size_t)i * RNCH + 1];
  float rsum = 0.f;
#pragma unroll
  for (int k = 0; k < SNCH; ++k) rsum += RS[(size_t)p * SNCH + k];
  const float* fi = (i < BN) ? of + (size_t)i * DD : af + (size_t)(i - BN) * DD;
  const float sii  = dot64(fi, fi);
  const float slpp = SLV[(size_t)p * BN + p];
  float Av = 2.f * rsum - slpp;       // remove diag from A
  Bv -= sii * slpp;                   // remove diag from B (loop included it)
  float M = 0.f;
  if (i >= 1) {
    const int j = i - 1;
    const float* f1 = (j < BN) ? of + (size_t)j * DD : af + (size_t)(j - BN) * DD;
    const float sim1 = dot64(fi, f1);
    const float sl1  = SLV[(size_t)p * BN + (j & (BN - 1))];
    S -= __expf(sim1); Av -= sl1; Bv -= sim1 * sl1;
    const float e2 = sim1 + sii, snd2 = sl1 + 0.5f;   // sl[i][i] = 0.5 exactly in ref
    if (i >= 2) {
      const int j2 = i - 2;
      const float* f2 = (j2 < BN) ? of + (size_t)j2 * DD : af + (size_t)(j2 - BN) * DD;
      const float sim2 = dot64(fi, f2);
      const float sl2  = SLV[(size_t)p * BN + (j2 & (BN - 1))];
      S -= __expf(sim2); Av -= sl2; Bv -= sim2 * sl2;
      const float e1 = sim2 + sim1, snd1 = sl2 + sl1;
      smax_merge(M, S, e1, 1.f); Av += snd1; Bv = fmaf(e1, snd1, Bv);
    }
    smax_merge(M, S, e2, 1.f); Av += snd2; Bv = fmaf(e2, snd2, Bv);
  }
  ROWL[i] = (M + logf(S)) * Av - Bv;
}

// ---------------- k_red: tiny final reduction ----------------
__global__ __launch_bounds__(1024) void k_red(const float* __restrict__ ws,
                                              float* __restrict__ out)
{
  const float* ROWL = ws + ROWL_OFF;
  const float* SLT  = ws + SLT_OFF;
  __shared__ float redL[1024], redT[1024];
  const int tid = threadIdx.x;
  float loss = ROWL[tid] + ROWL[tid + 1024] + ROWL[tid + 2048] + ROWL[tid + 3072];
  float tot  = SLT[tid];   // SGRID == 1024
  redL[tid] = loss; redT[tid] = tot;
  __syncthreads();
  for (int off = 512; off; off >>= 1) {
    if (tid < off) { redL[tid] += redL[tid + off]; redT[tid] += redT[tid + off]; }
    __syncthreads();
  }
  if (tid == 0) {
    out[0] = redL[0] / (float)((long long)BN2 * (BN2 - 1));
    out[1] = redT[0] / (float)((long long)BN * BN);
  }
}

extern "C" void kernel_launch(void* const* d_in, const int* in_sizes, int n_in,
                              void* d_out, int out_size, void* d_ws, size_t ws_size,
                              hipStream_t stream) {
  (void)in_sizes; (void)n_in; (void)out_size; (void)ws_size;
  const float* of = (const float*)d_in[0];   // original_feature  (16,128,64)
  const float* af = (const float*)d_in[1];   // augmented_feature (16,128,64)
  const float* os = (const float*)d_in[2];   // original_series   (16,96,128)
  float* ws = (float*)d_ws;
  k_pre  <<<776,        TPB,  0, stream>>>(os, ws);
  k_sig  <<<SGRID,      TPB,  0, stream>>>(ws);
  k_rows <<<RGRID,      TPB,  0, stream>>>(of, af, ws);
  k_corr <<<BN2 / TPB,  TPB,  0, stream>>>(of, af, ws);
  k_red  <<<1,          1024, 0, stream>>>(ws, (float*)d_out);
}

// Round 6
// 54.653 us; speedup vs baseline: 5.3062x; 2.3920x over previous
//
#include <hip/hip_runtime.h>
#include <hip/hip_bf16.h>
#include <math.h>

// Problem constants (B=16, N=128, D=64, T=96)
#define BN   2048
#define BN2  4096
#define DD   64
#define TT   96
#define NCH  128
#define TPB  256

// main-kernel tiling: one wave = 16 rows x 128 cols; 256 row-groups x 16 chunks
#define NCHK  16
#define CPW   (BN / NCHK)        // 128 col-pairs per wave
#define TPW   (CPW / 16)         // 8 MFMA col-tiles per wave
#define NWAVE (256 * NCHK)       // 4096 waves
#define GMAIN (NWAVE / 4)        // 1024 blocks of 4 waves

// ws layout (floats)
#define ST_OFF   0                          // [BN][TT] fp32 transposed series
#define SSQ_OFF  (ST_OFF + BN * TT)         // [BN]
#define FB_OFF   (SSQ_OFF + BN)             // [BN2][DD] bf16  (of rows 0..2047, af rows 2048..4095)
#define SB_OFF   (FB_OFF + BN2 * DD / 2)    // [BN][TT] bf16
#define SR_OFF   (SB_OFF + BN * TT / 2)     // [BN2][NCHK] softmax-denom partials
#define AR_OFF   (SR_OFF + BN2 * NCHK)      // [BN2][NCHK] A partials (2*slv sums)
#define BR_OFF   (AR_OFF + BN2 * NCHK)      // [BN2][NCHK] B partials
#define SLT_OFF  (BR_OFF + BN2 * NCHK)      // [NWAVE] slsum partials
#define ROWL_OFF (SLT_OFF + NWAVE)          // [BN2] per-row loss

typedef __bf16 bf16x8 __attribute__((ext_vector_type(8)));
typedef float  f32x4  __attribute__((ext_vector_type(4)));

#define FMA4(acc, v, q) acc = fmaf((v).x,(q).x, fmaf((v).y,(q).y, fmaf((v).z,(q).z, fmaf((v).w,(q).w,(acc)))))

__device__ __forceinline__ void smax_merge(float& m, float& s, float mo, float so) {
  float nm = fmaxf(m, mo);
  s = s * __expf(m - nm) + so * __expf(mo - nm);
  m = nm;
}

__device__ __forceinline__ float dot64(const float* a, const float* b) {
  float acc = 0.f;
#pragma unroll
  for (int d4 = 0; d4 < DD / 4; ++d4) {
    float4 x = ((const float4*)a)[d4], y = ((const float4*)b)[d4];
    FMA4(acc, x, y);
  }
  return acc;
}

__device__ __forceinline__ float dot96(const float* a, const float* b) {
  float acc = 0.f;
#pragma unroll
  for (int t4 = 0; t4 < TT / 4; ++t4) {
    float4 x = ((const float4*)a)[t4], y = ((const float4*)b)[t4];
    FMA4(acc, x, y);
  }
  return acc;
}

// ---------------- k_pre: transpose series (fp32+bf16), ssq, features->bf16 ----------------
__global__ __launch_bounds__(TPB) void k_pre(
    const float* __restrict__ of, const float* __restrict__ af,
    const float* __restrict__ os, float* __restrict__ ws)
{
  const int b = blockIdx.x, tid = threadIdx.x;
  if (b < 768) {                       // series transpose: 768*256 = BN*TT
    int idx = b * TPB + tid;
    int n = idx & (NCH - 1);
    int bt = idx >> 7;                 // [0, 16*96)
    int batch = bt / TT, t = bt - batch * TT;
    float v = os[(size_t)idx];         // os[batch][t][n], coalesced
    int p = batch * NCH + n;
    (ws + ST_OFF)[(size_t)p * TT + t] = v;
    ((__hip_bfloat16*)(ws + SB_OFF))[(size_t)p * TT + t] = __float2bfloat16(v);
  } else if (b < 776) {                // ssq: 8*256 = BN
    int p = (b - 768) * TPB + tid;
    const float* sp = os + (size_t)(p >> 7) * TT * NCH + (p & (NCH - 1));
    float acc = 0.f;
    for (int t = 0; t < TT; ++t) { float v = sp[(size_t)t * NCH]; acc = fmaf(v, v, acc); }
    (ws + SSQ_OFF)[p] = acc;
  } else {                             // feature -> bf16: 1024*256 = BN2*DD
    int g = (b - 776) * TPB + tid;
    float v = (g < BN * DD) ? of[g] : af[g - BN * DD];
    ((__hip_bfloat16*)(ws + FB_OFF))[g] = __float2bfloat16(v);
  }
}

// ---------------- k_main: fused MFMA sim + series-dist + online row sums ----------------
__global__ __launch_bounds__(TPB) void k_main(float* __restrict__ ws)
{
  const float* SSQ = ws + SSQ_OFF;
  const __hip_bfloat16* FB = (const __hip_bfloat16*)(ws + FB_OFF);
  const __hip_bfloat16* SB = (const __hip_bfloat16*)(ws + SB_OFF);
  float* SR  = ws + SR_OFF;
  float* AR  = ws + AR_OFF;
  float* BR  = ws + BR_OFF;
  float* SLT = ws + SLT_OFF;

  const int tid  = threadIdx.x;
  const int wid  = blockIdx.x * 4 + (tid >> 6);
  const int lane = tid & 63;
  const int g    = lane >> 4;          // 0..3
  const int r16  = lane & 15;          // 0..15
  const int rg    = wid & 255;         // row-group: block's 4 waves consecutive -> B-frag L1 reuse
  const int chunk = wid >> 8;          // 0..15
  const int RI = rg * 16;
  const int PB = RI & (BN - 1);
  const bool half1 = (RI >= BN);       // wave-uniform
  const int C0 = chunk * CPW;

  // A-fragments: held in registers for the whole kernel.
  // layout: lane holds A[row = r16][k = 8*g + j], j=0..7 -> bytes row*stride + 16*g (+64*kk)
  const bf16x8* FA = (const bf16x8*)(FB + (size_t)(RI + r16) * DD);
  const bf16x8 a0 = FA[g], a1 = FA[g + 4];
  const bf16x8* SA = (const bf16x8*)(SB + (size_t)(PB + r16) * TT);
  const bf16x8 sa0 = SA[g], sa1 = SA[g + 4], sa2 = SA[g + 8];

  float ssqr[4];
#pragma unroll
  for (int e = 0; e < 4; ++e) ssqr[e] = SSQ[PB + 4 * g + e];

  float Sacc[4], Aacc[4], Bacc[4];
#pragma unroll
  for (int e = 0; e < 4; ++e) { Sacc[e] = 0.f; Aacc[e] = 0.f; Bacc[e] = 0.f; }
  float slacc = 0.f;

  for (int jt = 0; jt < TPW; ++jt) {
    const int C = C0 + jt * 16;
    const bf16x8* BO = (const bf16x8*)(FB + (size_t)(C + r16) * DD);
    const bf16x8* BA = (const bf16x8*)(FB + (size_t)(BN + C + r16) * DD);
    const bf16x8* BS = (const bf16x8*)(SB + (size_t)(C + r16) * TT);
    const bf16x8 bo0 = BO[g], bo1 = BO[g + 4];
    const bf16x8 ba0 = BA[g], ba1 = BA[g + 4];
    const bf16x8 bs0 = BS[g], bs1 = BS[g + 4], bs2 = BS[g + 8];

    const f32x4 z = {0.f, 0.f, 0.f, 0.f};
    f32x4 simA = __builtin_amdgcn_mfma_f32_16x16x32_bf16(a0, bo0, z, 0, 0, 0);
    simA = __builtin_amdgcn_mfma_f32_16x16x32_bf16(a1, bo1, simA, 0, 0, 0);
    f32x4 simB = __builtin_amdgcn_mfma_f32_16x16x32_bf16(a0, ba0, z, 0, 0, 0);
    simB = __builtin_amdgcn_mfma_f32_16x16x32_bf16(a1, ba1, simB, 0, 0, 0);
    f32x4 sd = __builtin_amdgcn_mfma_f32_16x16x32_bf16(sa0, bs0, z, 0, 0, 0);
    sd = __builtin_amdgcn_mfma_f32_16x16x32_bf16(sa1, bs1, sd, 0, 0, 0);
    sd = __builtin_amdgcn_mfma_f32_16x16x32_bf16(sa2, bs2, sd, 0, 0, 0);

    const int pc = C + r16;            // D col = lane%16
    const float ssqc = SSQ[pc];
#pragma unroll
    for (int e = 0; e < 4; ++e) {
      const int pr = PB + 4 * g + e;   // D row = 4*(lane>>4)+reg
      const bool dg = (pr == pc);
      float dist = dg ? 0.f : (ssqr[e] + ssqc - 2.f * sd[e]);
      const float slv = __builtin_amdgcn_rcpf(1.f + __expf(0.5f * dist));
      slacc += slv;
      Aacc[e] += 2.f * slv;
      Bacc[e] = fmaf(slv, simA[e] + simB[e], Bacc[e]);
      float eA = __expf(simA[e]);
      float eB = __expf(simB[e]);
      if (half1) { eB = dg ? 0.f : eB; } else { eA = dg ? 0.f : eA; }  // mask true diag only
      Sacc[e] += eA + eB;
    }
  }

  // reduce over the 16 column-lanes of each group (rows identical within group)
#pragma unroll
  for (int off = 1; off < 16; off <<= 1) {
#pragma unroll
    for (int e = 0; e < 4; ++e) {
      Sacc[e] += __shfl_xor(Sacc[e], off);
      Aacc[e] += __shfl_xor(Aacc[e], off);
      Bacc[e] += __shfl_xor(Bacc[e], off);
    }
  }
#pragma unroll
  for (int off = 1; off < 64; off <<= 1) slacc += __shfl_xor(slacc, off);

  if (r16 == 0) {
#pragma unroll
    for (int e = 0; e < 4; ++e) {
      const int row = RI + 4 * g + e;
      SR[(size_t)row * NCHK + chunk] = Sacc[e];
      AR[(size_t)row * NCHK + chunk] = Aacc[e];
      BR[(size_t)row * NCHK + chunk] = Bacc[e];
    }
  }
  if (lane == 0) SLT[wid] = slacc;
}

// ---------------- k_corr: per-row exact corrections (fp32) ----------------
__global__ __launch_bounds__(TPB) void k_corr(
    const float* __restrict__ of, const float* __restrict__ af,
    float* __restrict__ ws)
{
  const float* ST  = ws + ST_OFF;
  const float* SSQ = ws + SSQ_OFF;
  const float* SR  = ws + SR_OFF;
  const float* AR  = ws + AR_OFF;
  const float* BR  = ws + BR_OFF;
  float* ROWL = ws + ROWL_OFF;

  const int i = blockIdx.x * TPB + threadIdx.x;   // one row per thread
  const int p = i & (BN - 1);
  float S = 0.f, Asum = 0.f, Bv = 0.f;
#pragma unroll
  for (int k = 0; k < NCHK; ++k) {
    S    += SR[(size_t)i * NCHK + k];
    Asum += AR[(size_t)i * NCHK + k];
    Bv   += BR[(size_t)i * NCHK + k];
  }
  const float* fi = (i < BN) ? of + (size_t)i * DD : af + (size_t)(i - BN) * DD;
  const float sii = dot64(fi, fi);
  float Av = Asum - 0.5f;              // remove diag slv (exactly 0.5)
  Bv -= sii * 0.5f;                    // remove diag sim*slv (loop included bf16 sim; negligible mismatch)
  float M = 0.f;
  if (i >= 1) {
    const int j = i - 1;
    const float* f1 = (j < BN) ? of + (size_t)j * DD : af + (size_t)(j - BN) * DD;
    const float sim1 = dot64(fi, f1);
    const int p1 = j & (BN - 1);
    const float d1 = SSQ[p] + SSQ[p1] - 2.f * dot96(ST + (size_t)p * TT, ST + (size_t)p1 * TT);
    const float sl1 = 1.f / (1.f + __expf(0.5f * d1));
    S -= __expf(sim1); Av -= sl1; Bv -= sim1 * sl1;
    const float e2 = sim1 + sii, snd2 = sl1 + 0.5f;   // sl[i][i] = sigmoid(0) = 0.5 exact
    if (i >= 2) {
      const int j2 = i - 2;
      const float* f2 = (j2 < BN) ? of + (size_t)j2 * DD : af + (size_t)(j2 - BN) * DD;
      const float sim2 = dot64(fi, f2);
      const int p2 = j2 & (BN - 1);
      const float d2 = SSQ[p] + SSQ[p2] - 2.f * dot96(ST + (size_t)p * TT, ST + (size_t)p2 * TT);
      const float sl2 = 1.f / (1.f + __expf(0.5f * d2));
      S -= __expf(sim2); Av -= sl2; Bv -= sim2 * sl2;
      const float e1 = sim2 + sim1, snd1 = sl2 + sl1;
      smax_merge(M, S, e1, 1.f); Av += snd1; Bv = fmaf(e1, snd1, Bv);
    }
    smax_merge(M, S, e2, 1.f); Av += snd2; Bv = fmaf(e2, snd2, Bv);
  }
  ROWL[i] = (M + logf(S)) * Av - Bv;
}

// ---------------- k_red: tiny final reduction ----------------
__global__ __launch_bounds__(1024) void k_red(const float* __restrict__ ws,
                                              float* __restrict__ out)
{
  const float* ROWL = ws + ROWL_OFF;
  const float* SLT  = ws + SLT_OFF;
  __shared__ float redL[1024], redT[1024];
  const int tid = threadIdx.x;
  float loss = ROWL[tid] + ROWL[tid + 1024] + ROWL[tid + 2048] + ROWL[tid + 3072];
  float tot  = SLT[tid]  + SLT[tid + 1024]  + SLT[tid + 2048]  + SLT[tid + 3072];
  redL[tid] = loss; redT[tid] = tot;
  __syncthreads();
  for (int off = 512; off; off >>= 1) {
    if (tid < off) { redL[tid] += redL[tid + off]; redT[tid] += redT[tid + off]; }
    __syncthreads();
  }
  if (tid == 0) {
    out[0] = redL[0] / (float)((long long)BN2 * (BN2 - 1));   // 4096*4095
    out[1] = redT[0] / (float)(2ll * BN * BN);                // slsum counted 2x
  }
}

extern "C" void kernel_launch(void* const* d_in, const int* in_sizes, int n_in,
                              void* d_out, int out_size, void* d_ws, size_t ws_size,
                              hipStream_t stream) {
  (void)in_sizes; (void)n_in; (void)out_size; (void)ws_size;
  const float* of = (const float*)d_in[0];   // original_feature  (16,128,64)
  const float* af = (const float*)d_in[1];   // augmented_feature (16,128,64)
  const float* os = (const float*)d_in[2];   // original_series   (16,96,128)
  float* ws = (float*)d_ws;
  k_pre  <<<1800,      TPB,  0, stream>>>(of, af, os, ws);
  k_main <<<GMAIN,     TPB,  0, stream>>>(ws);
  k_corr <<<BN2 / TPB, TPB,  0, stream>>>(of, af, ws);
  k_red  <<<1,         1024, 0, stream>>>(ws, (float*)d_out);
}

// Round 7
// 43.309 us; speedup vs baseline: 6.6960x; 1.2619x over previous
//
#include <hip/hip_runtime.h>
#include <hip/hip_bf16.h>
#include <math.h>

// Problem constants (B=16, N=128, D=64, T=96)
#define BN   2048
#define BN2  4096
#define DD   64
#define TT   96
#define NCH  128
#define TPB  256

// main-kernel tiling: one wave = 16 rows x 128 cols; 256 row-groups x 16 chunks
#define NCHK  16
#define CPW   (BN / NCHK)        // 128 col-pairs per wave
#define TPW   (CPW / 16)         // 8 MFMA col-tiles per wave
#define NWAVE (256 * NCHK)       // 4096 waves
#define GMAIN (NWAVE / 4)        // 1024 blocks of 4 waves

// ws layout (floats)
#define ST_OFF   0                          // [BN][TT] fp32 transposed series
#define SSQ_OFF  (ST_OFF + BN * TT)         // [BN]
#define FB_OFF   (SSQ_OFF + BN)             // [BN2][DD] bf16  (of rows 0..2047, af rows 2048..4095)
#define SB_OFF   (FB_OFF + BN2 * DD / 2)    // [BN][TT] bf16
#define SR_OFF   (SB_OFF + BN * TT / 2)     // [BN2][NCHK] softmax-denom partials
#define AR_OFF   (SR_OFF + BN2 * NCHK)      // [BN2][NCHK] A partials (2*slv sums)
#define BR_OFF   (AR_OFF + BN2 * NCHK)      // [BN2][NCHK] B partials
#define SLT_OFF  (BR_OFF + BN2 * NCHK)      // [NWAVE] slsum partials
#define ROWL_OFF (SLT_OFF + NWAVE)          // [BN2] per-row loss

typedef __bf16 bf16x8 __attribute__((ext_vector_type(8)));
typedef float  f32x4  __attribute__((ext_vector_type(4)));

union BU { __hip_bfloat16 h; unsigned short u; };

#define FMA4(acc, v, q) acc = fmaf((v).x,(q).x, fmaf((v).y,(q).y, fmaf((v).z,(q).z, fmaf((v).w,(q).w,(acc)))))

__device__ __forceinline__ void smax_merge(float& m, float& s, float mo, float so) {
  float nm = fmaxf(m, mo);
  s = s * __expf(m - nm) + so * __expf(mo - nm);
  m = nm;
}

__device__ __forceinline__ float dot64(const float* a, const float* b) {
  float acc = 0.f;
#pragma unroll
  for (int d4 = 0; d4 < DD / 4; ++d4) {
    float4 x = ((const float4*)a)[d4], y = ((const float4*)b)[d4];
    FMA4(acc, x, y);
  }
  return acc;
}

__device__ __forceinline__ float dot96(const float* a, const float* b) {
  float acc = 0.f;
#pragma unroll
  for (int t4 = 0; t4 < TT / 4; ++t4) {
    float4 x = ((const float4*)a)[t4], y = ((const float4*)b)[t4];
    FMA4(acc, x, y);
  }
  return acc;
}

__device__ __forceinline__ unsigned short f2bu(float v) {
  BU z; z.h = __float2bfloat16(v); return z.u;
}

// ---------------- k_pre: LDS-tiled series transpose + ssq; feature->bf16 ----------------
// blocks 0..15: one per batch (series). blocks 16..271: feature conversion (float4 each).
__global__ __launch_bounds__(TPB) void k_pre(
    const float* __restrict__ of, const float* __restrict__ af,
    const float* __restrict__ os, float* __restrict__ ws)
{
  const int b = blockIdx.x, tid = threadIdx.x;
  if (b < 16) {
    __shared__ float lds[TT * 129];          // padded [96][129] = 49.5 KB
    __shared__ float ssqp[TPB];
    float* ST  = ws + ST_OFF;
    float* SSQ = ws + SSQ_OFF;
    unsigned short* SB = (unsigned short*)(ws + SB_OFF);
    const int batch = b;

    const float4* os4 = (const float4*)(os + (size_t)batch * TT * NCH);
    for (int f4 = tid; f4 < TT * NCH / 4; f4 += TPB) {   // 3072, coalesced
      float4 v = os4[f4];
      int t = f4 >> 5, n4 = f4 & 31;                     // 32 float4 per t-row
      float* dst = lds + t * 129 + n4 * 4;
      dst[0] = v.x; dst[1] = v.y; dst[2] = v.z; dst[3] = v.w;
    }
    __syncthreads();
    {   // ssq: column sums, conflict-free (stride-129 rows)
      int n = tid & 127, half = tid >> 7;
      float acc = 0.f;
#pragma unroll
      for (int tt = 0; tt < TT / 2; ++tt) {
        float v = lds[(half * (TT / 2) + tt) * 129 + n];
        acc = fmaf(v, v, acc);
      }
      ssqp[tid] = acc;
    }
    __syncthreads();
    if (tid < NCH) SSQ[batch * NCH + tid] = ssqp[tid] + ssqp[tid + NCH];
    // ST fp32 rows + SB bf16 rows (float4 / ushort4 stores)
    for (int f = tid; f < NCH * (TT / 4); f += TPB) {    // 3072
      int n = f / (TT / 4), t4 = f % (TT / 4);
      float4 o;
      o.x = lds[(4 * t4 + 0) * 129 + n];
      o.y = lds[(4 * t4 + 1) * 129 + n];
      o.z = lds[(4 * t4 + 2) * 129 + n];
      o.w = lds[(4 * t4 + 3) * 129 + n];
      const size_t p = (size_t)batch * NCH + n;
      ((float4*)ST)[p * (TT / 4) + t4] = o;
      ushort4 ob = { f2bu(o.x), f2bu(o.y), f2bu(o.z), f2bu(o.w) };
      ((ushort4*)SB)[p * (TT / 4) + t4] = ob;
    }
  } else {
    // features -> bf16: 256 blocks x 256 threads x 1 float4
    unsigned short* FBs = (unsigned short*)(ws + FB_OFF);
    const int g4 = (b - 16) * TPB + tid;                 // [0, 65536)
    float4 v = (g4 < BN * DD / 4) ? ((const float4*)of)[g4]
                                  : ((const float4*)af)[g4 - BN * DD / 4];
    ushort4 o = { f2bu(v.x), f2bu(v.y), f2bu(v.z), f2bu(v.w) };
    ((ushort4*)FBs)[g4] = o;
  }
}

// ---------------- k_main: fused MFMA sim + series-dist + online row sums ----------------
__global__ __launch_bounds__(TPB) void k_main(float* __restrict__ ws)
{
  const float* SSQ = ws + SSQ_OFF;
  const __hip_bfloat16* FB = (const __hip_bfloat16*)(ws + FB_OFF);
  const __hip_bfloat16* SB = (const __hip_bfloat16*)(ws + SB_OFF);
  float* SR  = ws + SR_OFF;
  float* AR  = ws + AR_OFF;
  float* BR  = ws + BR_OFF;
  float* SLT = ws + SLT_OFF;

  const int tid  = threadIdx.x;
  const int wid  = blockIdx.x * 4 + (tid >> 6);
  const int lane = tid & 63;
  const int g    = lane >> 4;          // 0..3
  const int r16  = lane & 15;          // 0..15
  const int rg    = wid & 255;         // block's 4 waves: consecutive rg, same chunk -> L1 B reuse
  const int chunk = wid >> 8;          // 0..15
  const int RI = rg * 16;
  const int PB = RI & (BN - 1);
  const bool half1 = (RI >= BN);       // wave-uniform
  const int C0 = chunk * CPW;

  // A-fragments in registers for the whole kernel (m89 layout: row=lane%16, k=8*(lane>>4)+j)
  const bf16x8* FA = (const bf16x8*)(FB + (size_t)(RI + r16) * DD);
  const bf16x8 a0 = FA[g], a1 = FA[g + 4];
  const bf16x8* SA = (const bf16x8*)(SB + (size_t)(PB + r16) * TT);
  const bf16x8 sa0 = SA[g], sa1 = SA[g + 4], sa2 = SA[g + 8];

  float ssqr[4];
#pragma unroll
  for (int e = 0; e < 4; ++e) ssqr[e] = SSQ[PB + 4 * g + e];

  float Sacc[4], Aacc[4], Bacc[4];
#pragma unroll
  for (int e = 0; e < 4; ++e) { Sacc[e] = 0.f; Aacc[e] = 0.f; Bacc[e] = 0.f; }
  float slacc = 0.f;

  for (int jt = 0; jt < TPW; ++jt) {
    const int C = C0 + jt * 16;
    const bf16x8* BO = (const bf16x8*)(FB + (size_t)(C + r16) * DD);
    const bf16x8* BA = (const bf16x8*)(FB + (size_t)(BN + C + r16) * DD);
    const bf16x8* BS = (const bf16x8*)(SB + (size_t)(C + r16) * TT);
    const bf16x8 bo0 = BO[g], bo1 = BO[g + 4];
    const bf16x8 ba0 = BA[g], ba1 = BA[g + 4];
    const bf16x8 bs0 = BS[g], bs1 = BS[g + 4], bs2 = BS[g + 8];

    const f32x4 z = {0.f, 0.f, 0.f, 0.f};
    f32x4 simA = __builtin_amdgcn_mfma_f32_16x16x32_bf16(a0, bo0, z, 0, 0, 0);
    simA = __builtin_amdgcn_mfma_f32_16x16x32_bf16(a1, bo1, simA, 0, 0, 0);
    f32x4 simB = __builtin_amdgcn_mfma_f32_16x16x32_bf16(a0, ba0, z, 0, 0, 0);
    simB = __builtin_amdgcn_mfma_f32_16x16x32_bf16(a1, ba1, simB, 0, 0, 0);
    f32x4 sd = __builtin_amdgcn_mfma_f32_16x16x32_bf16(sa0, bs0, z, 0, 0, 0);
    sd = __builtin_amdgcn_mfma_f32_16x16x32_bf16(sa1, bs1, sd, 0, 0, 0);
    sd = __builtin_amdgcn_mfma_f32_16x16x32_bf16(sa2, bs2, sd, 0, 0, 0);

    const int pc = C + r16;            // D col = lane%16
    const float ssqc = SSQ[pc];
#pragma unroll
    for (int e = 0; e < 4; ++e) {
      const int pr = PB + 4 * g + e;   // D row = 4*(lane>>4)+reg
      const bool dg = (pr == pc);
      float dist = dg ? 0.f : (ssqr[e] + ssqc - 2.f * sd[e]);
      const float slv = __builtin_amdgcn_rcpf(1.f + __expf(0.5f * dist));
      slacc += slv;
      Aacc[e] += 2.f * slv;
      Bacc[e] = fmaf(slv, simA[e] + simB[e], Bacc[e]);
      float eA = __expf(simA[e]);
      float eB = __expf(simB[e]);
      if (half1) { eB = dg ? 0.f : eB; } else { eA = dg ? 0.f : eA; }  // mask true diag only
      Sacc[e] += eA + eB;
    }
  }

  // reduce over the 16 column-lanes of each group
#pragma unroll
  for (int off = 1; off < 16; off <<= 1) {
#pragma unroll
    for (int e = 0; e < 4; ++e) {
      Sacc[e] += __shfl_xor(Sacc[e], off);
      Aacc[e] += __shfl_xor(Aacc[e], off);
      Bacc[e] += __shfl_xor(Bacc[e], off);
    }
  }
#pragma unroll
  for (int off = 1; off < 64; off <<= 1) slacc += __shfl_xor(slacc, off);

  if (r16 == 0) {
#pragma unroll
    for (int e = 0; e < 4; ++e) {
      const int row = RI + 4 * g + e;
      SR[(size_t)row * NCHK + chunk] = Sacc[e];
      AR[(size_t)row * NCHK + chunk] = Aacc[e];
      BR[(size_t)row * NCHK + chunk] = Bacc[e];
    }
  }
  if (lane == 0) SLT[wid] = slacc;
}

// ---------------- k_corr: per-row exact corrections (fp32), 64 blocks x 64 ----------------
__global__ __launch_bounds__(64) void k_corr(
    const float* __restrict__ of, const float* __restrict__ af,
    float* __restrict__ ws)
{
  const float* ST  = ws + ST_OFF;
  const float* SSQ = ws + SSQ_OFF;
  const float* SR  = ws + SR_OFF;
  const float* AR  = ws + AR_OFF;
  const float* BR  = ws + BR_OFF;
  float* ROWL = ws + ROWL_OFF;

  const int i = blockIdx.x * 64 + threadIdx.x;    // one row per thread
  const int p = i & (BN - 1);
  float S = 0.f, Asum = 0.f, Bv = 0.f;
#pragma unroll
  for (int k = 0; k < NCHK; ++k) {
    S    += SR[(size_t)i * NCHK + k];
    Asum += AR[(size_t)i * NCHK + k];
    Bv   += BR[(size_t)i * NCHK + k];
  }
  const float* fi = (i < BN) ? of + (size_t)i * DD : af + (size_t)(i - BN) * DD;
  const float sii = dot64(fi, fi);
  float Av = Asum - 0.5f;              // remove diag slv (exactly 0.5)
  Bv -= sii * 0.5f;                    // remove diag sim*slv
  float M = 0.f;
  if (i >= 1) {
    const int j = i - 1;
    const float* f1 = (j < BN) ? of + (size_t)j * DD : af + (size_t)(j - BN) * DD;
    const float sim1 = dot64(fi, f1);
    const int p1 = j & (BN - 1);
    const float d1 = SSQ[p] + SSQ[p1] - 2.f * dot96(ST + (size_t)p * TT, ST + (size_t)p1 * TT);
    const float sl1 = 1.f / (1.f + __expf(0.5f * d1));
    S -= __expf(sim1); Av -= sl1; Bv -= sim1 * sl1;
    const float e2 = sim1 + sii, snd2 = sl1 + 0.5f;   // sl[i][i] = sigmoid(0) = 0.5 exact
    if (i >= 2) {
      const int j2 = i - 2;
      const float* f2 = (j2 < BN) ? of + (size_t)j2 * DD : af + (size_t)(j2 - BN) * DD;
      const float sim2 = dot64(fi, f2);
      const int p2 = j2 & (BN - 1);
      const float d2 = SSQ[p] + SSQ[p2] - 2.f * dot96(ST + (size_t)p * TT, ST + (size_t)p2 * TT);
      const float sl2 = 1.f / (1.f + __expf(0.5f * d2));
      S -= __expf(sim2); Av -= sl2; Bv -= sim2 * sl2;
      const float e1 = sim2 + sim1, snd1 = sl2 + sl1;
      smax_merge(M, S, e1, 1.f); Av += snd1; Bv = fmaf(e1, snd1, Bv);
    }
    smax_merge(M, S, e2, 1.f); Av += snd2; Bv = fmaf(e2, snd2, Bv);
  }
  ROWL[i] = (M + logf(S)) * Av - Bv;
}

// ---------------- k_red: tiny final reduction ----------------
__global__ __launch_bounds__(1024) void k_red(const float* __restrict__ ws,
                                              float* __restrict__ out)
{
  const float* ROWL = ws + ROWL_OFF;
  const float* SLT  = ws + SLT_OFF;
  __shared__ float redL[1024], redT[1024];
  const int tid = threadIdx.x;
  float loss = ROWL[tid] + ROWL[tid + 1024] + ROWL[tid + 2048] + ROWL[tid + 3072];
  float tot  = SLT[tid]  + SLT[tid + 1024]  + SLT[tid + 2048]  + SLT[tid + 3072];
  redL[tid] = loss; redT[tid] = tot;
  __syncthreads();
  for (int off = 512; off; off >>= 1) {
    if (tid < off) { redL[tid] += redL[tid + off]; redT[tid] += redT[tid + off]; }
    __syncthreads();
  }
  if (tid == 0) {
    out[0] = redL[0] / (float)((long long)BN2 * (BN2 - 1));   // 4096*4095
    out[1] = redT[0] / (float)(2ll * BN * BN);                // slsum counted 2x
  }
}

extern "C" void kernel_launch(void* const* d_in, const int* in_sizes, int n_in,
                              void* d_out, int out_size, void* d_ws, size_t ws_size,
                              hipStream_t stream) {
  (void)in_sizes; (void)n_in; (void)out_size; (void)ws_size;
  const float* of = (const float*)d_in[0];   // original_feature  (16,128,64)
  const float* af = (const float*)d_in[1];   // augmented_feature (16,128,64)
  const float* os = (const float*)d_in[2];   // original_series   (16,96,128)
  float* ws = (float*)d_ws;
  k_pre  <<<272,   TPB,  0, stream>>>(of, af, os, ws);
  k_main <<<GMAIN, TPB,  0, stream>>>(ws);
  k_corr <<<64,    64,   0, stream>>>(of, af, ws);
  k_red  <<<1,     1024, 0, stream>>>(ws, (float*)d_out);
}